// Round 8
// baseline (602.244 us; speedup 1.0000x reference)
//
#include <hip/hip_runtime.h>
#include <stdint.h>

#define EN 64
#define BN 32
#define PN 197
#define DIN 768
#define HH 512
#define RHO_ 4.0f

typedef __attribute__((ext_vector_type(8))) short bf16x8;
typedef __attribute__((ext_vector_type(4))) float f32x4;

__device__ __forceinline__ ushort f2bf(float f){
  unsigned u = __float_as_uint(f);
  u += 0x7FFFu + ((u >> 16) & 1u);
  return (ushort)(u >> 16);
}
__device__ __forceinline__ float bf2f(ushort h){ return __uint_as_float(((unsigned)h) << 16); }

// async global->LDS, 16B per lane; LDS dest = wave-uniform base + lane*16
#define GLOAD_LDS16(g, l) __builtin_amdgcn_global_load_lds( \
    (const __attribute__((address_space(1))) void*)(g), \
    (__attribute__((address_space(3))) void*)(l), 16, 0, 0)

// ---------------- prep: bf16 casts + scaled bias ----------------
__global__ __launch_bounds__(256) void prep_kernel(
    const float* __restrict__ etok, const float* __restrict__ mtok,
    const float* __restrict__ ecls, const float* __restrict__ bq,
    ushort* __restrict__ a_ent, ushort* __restrict__ a_men, ushort* __restrict__ a_cls,
    float* __restrict__ bq_s)
{
  int g = blockIdx.x*256 + threadIdx.x;
  int st = gridDim.x*256;
  const float s = 0.04419417382415922f; // 1/sqrt(512)
  for (int i=g; i<(EN*PN*DIN)/4; i+=st){
    float4 v = ((const float4*)etok)[i];
    ushort4 o; o.x=f2bf(v.x); o.y=f2bf(v.y); o.z=f2bf(v.z); o.w=f2bf(v.w);
    ((ushort4*)a_ent)[i] = o;
  }
  for (int i=g; i<(BN*PN*DIN)/4; i+=st){
    float4 v = ((const float4*)mtok)[i];
    ushort4 o; o.x=f2bf(v.x); o.y=f2bf(v.y); o.z=f2bf(v.z); o.w=f2bf(v.w);
    ((ushort4*)a_men)[i] = o;
  }
  for (int i=g; i<(EN*DIN)/4; i+=st){
    float4 v = ((const float4*)ecls)[i];
    ushort4 o; o.x=f2bf(v.x); o.y=f2bf(v.y); o.z=f2bf(v.z); o.w=f2bf(v.w);
    ((ushort4*)a_cls)[i] = o;
  }
  for (int i=g; i<HH; i+=st) bq_s[i] = bq[i]*s;
}

// ---------------- weight transpose via LDS tiles ----------------
__global__ __launch_bounds__(256) void w_transpose(
    const float* __restrict__ Wq, const float* __restrict__ Wk,
    const float* __restrict__ Wv, const float* __restrict__ Wc,
    ushort* __restrict__ Wt)
{
  __shared__ float tl[64][65];
  int mat = blockIdx.z;
  const float* src = (mat==0)?Wq:(mat==1)?Wk:(mat==2)?Wv:Wc;
  float sc = (mat==0)? 0.04419417382415922f : 1.0f;
  int k0 = blockIdx.x*64;
  int n0 = blockIdx.y*64;
  int tid = threadIdx.x;
  int c = tid & 63, r0 = tid >> 6;
  #pragma unroll
  for (int i=0;i<16;++i){
    int r = r0 + i*4;
    tl[r][c] = src[(size_t)(k0+r)*HH + n0+c];
  }
  __syncthreads();
  ushort* dst = Wt + (size_t)mat*HH*DIN;
  #pragma unroll
  for (int i=0;i<16;++i){
    int r = r0 + i*4;
    dst[(size_t)(n0+r)*DIN + k0+c] = f2bf(tl[c][r]*sc);
  }
}

// ---------------- projection GEMMs: C = A @ Wt^T + bias ----------------
__global__ __launch_bounds__(256) void gemm_proj(
    const ushort* __restrict__ a_ent, const ushort* __restrict__ a_men, const ushort* __restrict__ a_cls,
    const ushort* __restrict__ Wt,
    const float* __restrict__ bq_s, const float* __restrict__ bk,
    const float* __restrict__ bv, const float* __restrict__ bc,
    ushort* __restrict__ qo, ushort* __restrict__ ko, ushort* __restrict__ vo,
    float* __restrict__ co)
{
  int x = blockIdx.x;
  int op, mt;
  if (x < 99)        { op = 0; mt = x; }
  else if (x < 149)  { op = 1; mt = x - 99; }
  else if (x < 199)  { op = 2; mt = x - 149; }
  else               { op = 3; mt = 0; }
  int M = (op==0)? EN*PN : (op==3)? EN : BN*PN;
  int m0 = mt*128;
  const ushort* A  = (op==0)? a_ent : (op==3)? a_cls : a_men;
  const ushort* Bw = Wt + (size_t)op*HH*DIN;
  const float* bias = (op==0)? bq_s : (op==1)? bk : (op==2)? bv : bc;
  int n0 = blockIdx.y*128;
  int Mm1 = M-1;

  __shared__ ushort As[128*40];
  __shared__ ushort Bs[128*40];
  int tid = threadIdx.x;
  int lane = tid & 63, wid = tid >> 6;
  int l15 = lane & 15, lg = lane >> 4;
  int wm = wid >> 1, wn = wid & 1;

  f32x4 acc[16];
  #pragma unroll
  for (int i=0;i<16;++i){ f32x4 z = {0.f,0.f,0.f,0.f}; acc[i] = z; }

  bf16x8 sA[2], sB[2];
  #pragma unroll
  for (int i=0;i<2;++i){
    int u = tid + i*256; int row = u>>2; int ko8 = (u&3)*8;
    int rA = m0+row; rA = rA>Mm1 ? Mm1 : rA;
    sA[i] = *(const bf16x8*)(A  + (size_t)rA*DIN + ko8);
    sB[i] = *(const bf16x8*)(Bw + (size_t)(n0+row)*DIN + ko8);
  }
  for (int kt=0; kt<DIN/32; ++kt){
    #pragma unroll
    for (int i=0;i<2;++i){
      int u = tid + i*256; int row = u>>2; int ko8 = (u&3)*8;
      *(bf16x8*)(&As[row*40 + ko8]) = sA[i];
      *(bf16x8*)(&Bs[row*40 + ko8]) = sB[i];
    }
    __syncthreads();
    if (kt < DIN/32 - 1){
      int k0 = (kt+1)*32;
      #pragma unroll
      for (int i=0;i<2;++i){
        int u = tid + i*256; int row = u>>2; int ko8 = (u&3)*8;
        int rA = m0+row; rA = rA>Mm1 ? Mm1 : rA;
        sA[i] = *(const bf16x8*)(A  + (size_t)rA*DIN + k0 + ko8);
        sB[i] = *(const bf16x8*)(Bw + (size_t)(n0+row)*DIN + k0 + ko8);
      }
    }
    bf16x8 af[4], bfg[4];
    #pragma unroll
    for (int t=0;t<4;++t){
      af[t]  = *(const bf16x8*)(&As[(wm*64 + t*16 + l15)*40 + lg*8]);
      bfg[t] = *(const bf16x8*)(&Bs[(wn*64 + t*16 + l15)*40 + lg*8]);
    }
    #pragma unroll
    for (int am=0; am<4; ++am)
      #pragma unroll
      for (int bn=0; bn<4; ++bn)
        acc[am*4+bn] = __builtin_amdgcn_mfma_f32_16x16x32_bf16(af[am], bfg[bn], acc[am*4+bn], 0, 0, 0);
    __syncthreads();
  }

  #pragma unroll
  for (int bn=0; bn<4; ++bn){
    int col = n0 + wn*64 + bn*16 + l15;
    float bval = bias[col];
    #pragma unroll
    for (int am=0; am<4; ++am){
      #pragma unroll
      for (int r=0;r<4;++r){
        int row = m0 + wm*64 + am*16 + lg*4 + r;
        if (row < M){
          float v = acc[am*4+bn][r] + bval;
          if (op==3)      co[(size_t)row*HH + col] = v;
          else if (op==0) qo[(size_t)row*HH + col] = f2bf(v);
          else if (op==1) ko[(size_t)row*HH + col] = f2bf(v);
          else            vo[(size_t)row*HH + col] = f2bf(v);
        }
      }
    }
  }
}

// ---------------- fused attention: 256-thr (4-wave) blocks, 2 blocks/CU ----------------
// block=(b,e-pair); wave owns slot = pass*4+wid (16 rows), 4 passes x 8 k-chunks of 64k.
// k staged via global_load_lds (source-side XOR swizzle, linear LDS dest, 0 conflicts).
// Two independent 4-wave blocks per CU overlap each other's barrier/staging stalls.
__global__ __launch_bounds__(256) void attn_kernel(
    const ushort* __restrict__ qw, const ushort* __restrict__ kw, const ushort* __restrict__ vw,
    const float* __restrict__ cls_fc, const float* __restrict__ maskp,
    const float* __restrict__ mcls, const float* __restrict__ ecls,
    const float* __restrict__ lng, const float* __restrict__ lnb,
    float* __restrict__ outp)
{
  int bid = blockIdx.x;
  int b = bid >> 5;
  int e0 = (bid & 31) * 2;

  __shared__ ushort klds[2][1664*8];   // [buf][unit(col*8+j)*8]; 208 cols x 64 k, 16B units
  __shared__ float w_lds[2][208];
  __shared__ float red[16];

  int tid = threadIdx.x;
  int lane = tid & 63, wid = tid >> 6;       // 4 waves
  int l15 = lane & 15, lg = (lane >> 4) & 3;

  for (int i=tid; i<416; i+=256) ((float*)w_lds)[i] = 0.f;

  const ushort* kb  = kw + (size_t)b*PN*HH;
  const ushort* qb0 = qw + (size_t)e0*PN*HH;
  const ushort* qb1 = qw + (size_t)(e0+1)*PN*HH;

  // stage chunk kc (all 208 cols x 64 k) into klds[bf]; unit (col,j) holds
  // global k[col][kc*64 + (j^(col&7))*8 ..+8]; LDS dest linear.
  auto issue = [&](int bf, int kc){
    #pragma unroll
    for (int i=0;i<7;++i){
      int L = tid + i*256;
      if (L < 1664){
        int col = L >> 3, j = L & 7;
        int cg = col > 196 ? 196 : col;
        const ushort* src = kb + (size_t)cg*HH + kc*64 + ((j ^ (col & 7)) * 8);
        ushort* dst = &klds[bf][ (wid*64 + i*256) * 8 ];   // wave-uniform base
        GLOAD_LDS16(src, dst);
      }
    }
  };

  f32x4 acc[2][13];
  #pragma unroll
  for (int e2=0;e2<2;++e2)
    #pragma unroll
    for (int i=0;i<13;++i){ f32x4 z={0.f,0.f,0.f,0.f}; acc[e2][i]=z; }

  issue(0, 0);
  // q fragments for chunk 0 (pass 0: slot = wid <= 3, rows valid)
  bf16x8 qc[2][2];
  {
    int r0 = wid*16 + l15;
    const ushort* a0 = qb0 + (size_t)r0*HH + lg*8;
    const ushort* a1 = qb1 + (size_t)r0*HH + lg*8;
    qc[0][0] = *(const bf16x8*)a0; qc[0][1] = *(const bf16x8*)(a0+32);
    qc[1][0] = *(const bf16x8*)a1; qc[1][1] = *(const bf16x8*)(a1+32);
  }

  #pragma unroll 1
  for (int g=0; g<32; ++g){
    int pass = g >> 3, kc = g & 7;
    int slot = pass*4 + wid;
    bool active = slot < 13;
    __syncthreads();                       // chunk g landed in klds[g&1]; prev reads done
    if (g < 31) issue((g+1)&1, (g+1)&7);   // stage next chunk (overlaps compute)
    bf16x8 qn[2][2];
    if (g < 31){                           // prefetch q frags for chunk g+1
      int np = (g+1)>>3, nkc = (g+1)&7;
      int ns = np*4 + wid; ns = ns > 12 ? 12 : ns;
      int nr = ns*16 + l15; nr = nr > 196 ? 196 : nr;
      const ushort* a0 = qb0 + (size_t)nr*HH + nkc*64 + lg*8;
      const ushort* a1 = qb1 + (size_t)nr*HH + nkc*64 + lg*8;
      qn[0][0] = *(const bf16x8*)a0; qn[0][1] = *(const bf16x8*)(a0+32);
      qn[1][0] = *(const bf16x8*)a1; qn[1][1] = *(const bf16x8*)(a1+32);
    }
    if (active){
      const ushort* kbase = &klds[g&1][0];
      __builtin_amdgcn_s_setprio(1);
      #pragma unroll
      for (int s=0; s<2; ++s){
        int ru = s*4 + lg;
        #pragma unroll
        for (int ct=0; ct<13; ++ct){
          int lcol = ct*16 + l15;
          bf16x8 bfr = *(const bf16x8*)(kbase + (size_t)(lcol*8 + (ru ^ (lcol&7)))*8);
          acc[0][ct] = __builtin_amdgcn_mfma_f32_16x16x32_bf16(qc[0][s], bfr, acc[0][ct], 0,0,0);
          acc[1][ct] = __builtin_amdgcn_mfma_f32_16x16x32_bf16(qc[1][s], bfr, acc[1][ct], 0,0,0);
        }
      }
      __builtin_amdgcn_s_setprio(0);
    }
    #pragma unroll
    for (int s=0; s<2; ++s){ qc[0][s]=qn[0][s]; qc[1][s]=qn[1][s]; }

    if (kc == 7){                          // end of pass: softmax + col-sum
      if (active){
        int rt = slot;
        #pragma unroll
        for (int e2=0; e2<2; ++e2){
          if (l15 >= 5){                   // cols 197..207 invalid (ct=12)
            f32x4 ninf = {-1e30f,-1e30f,-1e30f,-1e30f};
            acc[e2][12] = ninf;
          }
          if (rt==0 && lg==0){             // additive mask on query-row 0
            #pragma unroll
            for (int ct=0; ct<13; ++ct){
              int col = ct*16 + l15;
              if (col < 197) acc[e2][ct][0] += RHO_ * maskp[b*PN + col];
            }
          }
          float mrow[4], inv[4];
          #pragma unroll
          for (int r=0;r<4;++r){
            float m = acc[e2][0][r];
            #pragma unroll
            for (int ct=1; ct<13; ++ct) m = fmaxf(m, acc[e2][ct][r]);
            m = fmaxf(m, __shfl_xor(m,1));
            m = fmaxf(m, __shfl_xor(m,2));
            m = fmaxf(m, __shfl_xor(m,4));
            m = fmaxf(m, __shfl_xor(m,8));
            mrow[r] = m;
          }
          #pragma unroll
          for (int r=0;r<4;++r){
            float sm = 0.f;
            #pragma unroll
            for (int ct=0; ct<13; ++ct){
              float ev = __expf(acc[e2][ct][r] - mrow[r]);
              acc[e2][ct][r] = ev;
              sm += ev;
            }
            sm += __shfl_xor(sm,1); sm += __shfl_xor(sm,2);
            sm += __shfl_xor(sm,4); sm += __shfl_xor(sm,8);
            int prow = rt*16 + lg*4 + r;
            inv[r] = (prow < PN) ? 1.0f/sm : 0.f;
          }
          #pragma unroll
          for (int ct=0; ct<13; ++ct){
            float cs = acc[e2][ct][0]*inv[0] + acc[e2][ct][1]*inv[1]
                     + acc[e2][ct][2]*inv[2] + acc[e2][ct][3]*inv[3];
            cs += __shfl_xor(cs,16);
            cs += __shfl_xor(cs,32);
            if (lg==0) atomicAdd(&w_lds[e2][ct*16 + l15], cs);
          }
        }
      }
      if (pass < 3){                       // reset acc for next pass
        #pragma unroll
        for (int e2=0;e2<2;++e2)
          #pragma unroll
          for (int i=0;i<13;++i){ f32x4 z={0.f,0.f,0.f,0.f}; acc[e2][i]=z; }
      }
    }
  }
  __syncthreads();

  // phase 2: ctx[h] = (1/197) * sum_q w[q]*v[b,q,h]; thread owns h = tid, tid+256
  const ushort* vb = vw + (size_t)b*PN*HH;
  float cA0=0.f, cA1=0.f, cB0=0.f, cB1=0.f;
  #pragma unroll 4
  for (int q=0; q<PN; ++q){
    float v0 = bf2f(vb[(size_t)q*HH + tid]);
    float v1 = bf2f(vb[(size_t)q*HH + tid + 256]);
    float w0 = w_lds[0][q], w1 = w_lds[1][q];
    cA0 += w0*v0; cA1 += w0*v1;
    cB0 += w1*v0; cB1 += w1*v1;
  }
  const float invP = 1.0f/197.0f;
  cA0*=invP; cA1*=invP; cB0*=invP; cB1*=invP;

  float sx = cA0+cA1, sxx = cA0*cA0+cA1*cA1;
  float sy = cB0+cB1, syy = cB0*cB0+cB1*cB1;
  #pragma unroll
  for (int off=32; off; off>>=1){
    sx += __shfl_down(sx, off); sxx += __shfl_down(sxx, off);
    sy += __shfl_down(sy, off); syy += __shfl_down(syy, off);
  }
  if (lane==0){ red[wid*4+0]=sx; red[wid*4+1]=sxx; red[wid*4+2]=sy; red[wid*4+3]=syy; }
  __syncthreads();
  float s1A = red[0]+red[4]+red[8]+red[12];
  float s2A = red[1]+red[5]+red[9]+red[13];
  float s1B = red[2]+red[6]+red[10]+red[14];
  float s2B = red[3]+red[7]+red[11]+red[15];
  float muA = s1A*(1.f/512.f), muB = s1B*(1.f/512.f);
  float varA = s2A*(1.f/512.f) - muA*muA;
  float varB = s2B*(1.f/512.f) - muB*muB;
  float rsA = rsqrtf(varA + 1e-5f), rsB = rsqrtf(varB + 1e-5f);

  int h0 = tid, h1 = tid + 256;
  float g0=lng[h0], g1=lng[h1], bb0=lnb[h0], bb1=lnb[h1];
  float fA0 = cls_fc[(size_t)e0*HH + h0],     fA1 = cls_fc[(size_t)e0*HH + h1];
  float fB0 = cls_fc[(size_t)(e0+1)*HH + h0], fB1 = cls_fc[(size_t)(e0+1)*HH + h1];
  float dA = ((cA0-muA)*rsA*g0 + bb0)*fA0 + ((cA1-muA)*rsA*g1 + bb1)*fA1;
  float dB = ((cB0-muB)*rsB*g0 + bb0)*fB0 + ((cB1-muB)*rsB*g1 + bb1)*fB1;

  // g2g: 768 dims over 256 threads (3 each)
  int j = 3*tid;
  float m0v = mcls[b*DIN + j], m1v = mcls[b*DIN + j+1], m2v = mcls[b*DIN + j+2];
  dA += m0v*ecls[(size_t)e0*DIN + j] + m1v*ecls[(size_t)e0*DIN + j+1] + m2v*ecls[(size_t)e0*DIN + j+2];
  dB += m0v*ecls[(size_t)(e0+1)*DIN + j] + m1v*ecls[(size_t)(e0+1)*DIN + j+1] + m2v*ecls[(size_t)(e0+1)*DIN + j+2];

  __syncthreads();
  #pragma unroll
  for (int off=32; off; off>>=1){ dA += __shfl_down(dA, off); dB += __shfl_down(dB, off); }
  if (lane==0){ red[wid*2+0]=dA; red[wid*2+1]=dB; }
  __syncthreads();
  if (tid==0){
    outp[b*EN + e0]   = 0.5f*(red[0]+red[2]+red[4]+red[6]);
    outp[b*EN + e0+1] = 0.5f*(red[1]+red[3]+red[5]+red[7]);
  }
}

extern "C" void kernel_launch(void* const* d_in, const int* in_sizes, int n_in,
                              void* d_out, int out_size, void* d_ws, size_t ws_size,
                              hipStream_t stream)
{
  (void)in_sizes; (void)n_in; (void)out_size; (void)ws_size;
  const float* ecls = (const float*)d_in[0];
  const float* etok = (const float*)d_in[1];
  const float* mcls = (const float*)d_in[2];
  const float* mtok = (const float*)d_in[3];
  const float* maskp= (const float*)d_in[4];
  const float* Wq   = (const float*)d_in[5];
  const float* bq   = (const float*)d_in[6];
  const float* Wk   = (const float*)d_in[7];
  const float* bk   = (const float*)d_in[8];
  const float* Wv   = (const float*)d_in[9];
  const float* bv   = (const float*)d_in[10];
  const float* Wc   = (const float*)d_in[11];
  const float* bc   = (const float*)d_in[12];
  const float* lng  = (const float*)d_in[13];
  const float* lnb  = (const float*)d_in[14];

  char* ws = (char*)d_ws;
  size_t off = 0;
  auto take = [&](size_t bytes){ char* p = ws + off; off += (bytes + 255) & ~(size_t)255; return p; };
  ushort* a_ent = (ushort*)take((size_t)EN*PN*DIN*2);
  ushort* a_men = (ushort*)take((size_t)BN*PN*DIN*2);
  ushort* a_cls = (ushort*)take((size_t)EN*DIN*2);
  ushort* Wt    = (ushort*)take((size_t)4*HH*DIN*2);
  float*  bq_s  = (float*)take((size_t)HH*4);
  ushort* qo    = (ushort*)take((size_t)EN*PN*HH*2);
  ushort* ko    = (ushort*)take((size_t)BN*PN*HH*2);
  ushort* vo    = (ushort*)take((size_t)BN*PN*HH*2);
  float*  co    = (float*)take((size_t)EN*HH*4);

  prep_kernel<<<1024, 256, 0, stream>>>(etok, mtok, ecls, bq, a_ent, a_men, a_cls, bq_s);
  w_transpose<<<dim3(12,8,4), 256, 0, stream>>>(Wq, Wk, Wv, Wc, Wt);
  gemm_proj<<<dim3(200,4,1), 256, 0, stream>>>(a_ent, a_men, a_cls, Wt,
                                               bq_s, bk, bv, bc, qo, ko, vo, co);
  attn_kernel<<<1024, 256, 0, stream>>>(qo, ko, vo, co, maskp, mcls, ecls,
                                        lng, lnb, (float*)d_out);
}